// Round 14
// baseline (478.126 us; speedup 1.0000x reference)
//
#include <hip/hip_runtime.h>
#include <hip/hip_bf16.h>

// BasicBlock via chunked shift-GEMM bf16 MFMA. R13: 2-IMAGE PAIRING.
// Diagnosis: all prior variants were L2-BW-bound on per-step weight
// re-reads (A 4KB/wave-step + B staging ~= 55 B/cy/CU ~= per-CU L2 path).
// Fix: each block computes the same (pt, co-tile) for TWO images, reusing
// every A-frag for 32 MFMA (2 x 16). A-traffic halves; the two images'
// READB/MFMA interleave self-hides LDS latency (no bq dbuf needed).
// Grid 784 = 16 n-pairs x 49 pt. LDS: 2 windows x dbuf = 61.4KB; 2
// blocks/CU. Regs ~230 @ launch_bounds(256,2). Keeps: ci chunks of 32,
// mid-chunk stage (s==3 img0, s==4 img1), address-select zero-row border
// masking, areg dbuf, setprio, XCD swizzle (784=8*98 bijective).

typedef __attribute__((ext_vector_type(8))) short bf16x8;
typedef __attribute__((ext_vector_type(4))) float f32x4;
typedef __attribute__((ext_vector_type(4))) unsigned int uint4v;

#define C_CH   256
#define HW_IMG 3136
#define CHW    802816     // 256*3136
#define WELEM  589824     // 256*2304
#define RSTR   40         // LDS row stride in ushorts (32 data + 8 pad) = 80B
#define BUFE   7680       // 192*40 ushorts per window buffer (15360B)
#define IMG1B  15360      // img1 window region base (ushorts)
#define ZROW   30720      // zero row after both window regions
#define NCH    8          // ci chunks of 32
#define NSTEP  72         // 8 chunks * 9 taps

__device__ __forceinline__ ushort f2bf(float f){
    union{__hip_bfloat16 h; ushort u;} c; c.h = __float2bfloat16(f); return c.u;
}

__global__ __launch_bounds__(256) void prep_kernel(
    const float* __restrict__ w1, const float* __restrict__ w2,
    const float* __restrict__ g1, const float* __restrict__ b1,
    const float* __restrict__ m1, const float* __restrict__ v1,
    const float* __restrict__ g2, const float* __restrict__ b2,
    const float* __restrict__ m2, const float* __restrict__ v2,
    ushort* __restrict__ wf1, ushort* __restrict__ wf2,
    float* __restrict__ bn, ushort* __restrict__ zb)
{
    int gid = blockIdx.x * 256 + threadIdx.x;
    // frag-packed: d = (((c*9+r)*16 + ct)*64 + l)*8 + j
    // co = ct*16 + (l&15), ci = c*32 + (l>>4)*8 + j, tap r
    if (gid < WELEM) {
        int j = gid & 7, l = (gid >> 3) & 63, ct = (gid >> 9) & 15, rr = gid >> 13;
        int c = rr / 9, r = rr - c * 9;
        int co = ct * 16 + (l & 15);
        int ci = c * 32 + (l >> 4) * 8 + j;
        wf1[gid] = f2bf(w1[(co * C_CH + ci) * 9 + r]);
    }
    int g2i = gid - WELEM;
    if (g2i >= 0 && g2i < WELEM) {
        int j = g2i & 7, l = (g2i >> 3) & 63, ct = (g2i >> 9) & 15, rr = g2i >> 13;
        int c = rr / 9, r = rr - c * 9;
        int co = ct * 16 + (l & 15);
        int ci = c * 32 + (l >> 4) * 8 + j;
        wf2[g2i] = f2bf(w2[(co * C_CH + ci) * 9 + r]);
    }
    if (gid < C_CH) {
        float i1 = g1[gid] * rsqrtf(v1[gid] + 1e-5f);
        bn[gid]            = i1;
        bn[C_CH + gid]     = b1[gid] - m1[gid] * i1;
        float i2 = g2[gid] * rsqrtf(v2[gid] + 1e-5f);
        bn[2*C_CH + gid]   = i2;
        bn[3*C_CH + gid]   = b2[gid] - m2[gid] * i2;
    }
    if (gid < 512) zb[gid] = 0;
}

// x [n][ci][p] f32 -> xT [n][p][ci] bf16
__global__ __launch_bounds__(256) void xpose_kernel(
    const float* __restrict__ x, ushort* __restrict__ xT)
{
    __shared__ ushort T[64 * 72];
    int tid = threadIdx.x;
    int b = blockIdx.x;                  // 32*49*4
    int n = b / 196, rem = b % 196;
    int pb = rem >> 2, cb = rem & 3;
    int lane = tid & 63, cr = tid >> 6;
    const float* xp = x + ((size_t)(n * C_CH + cb * 64)) * HW_IMG + pb * 64 + lane;
#pragma unroll
    for (int j = 0; j < 16; ++j) {
        int cil = cr * 16 + j;
        T[lane * 72 + cil] = f2bf(xp[(size_t)cil * HW_IMG]);
    }
    __syncthreads();
#pragma unroll
    for (int it = 0; it < 2; ++it) {
        int slot = it * 256 + tid;       // 512 slots = 64 rows x 8 granules
        int p = slot >> 3, g = slot & 7;
        uint4v v = *(const uint4v*)&T[p * 72 + g * 8];
        *(uint4v*)(xT + ((size_t)n * HW_IMG + pb * 64 + p) * C_CH + cb * 64 + g * 8) = v;
    }
}

// read tap s's 4 B-frags from window at `base` into NAMED array `dst`
#define READB(dst, base, s)                                                  \
    {                                                                        \
        const int dw_ = (s) % 3 - 1;                                         \
        const int off_ = ((s) / 3 - 1) * 56 * RSTR + dw_ * RSTR + (base);    \
        _Pragma("unroll")                                                    \
        for (int nc_ = 0; nc_ < 4; ++nc_) {                                  \
            bool ok_ = (dw_ == -1) ? wLa[nc_]                                \
                                   : ((dw_ == 1) ? wRa[nc_] : true);         \
            int idx_ = ok_ ? (vbe[nc_] + off_) : zidx;                       \
            dst[nc_] = *(const bf16x8*)&B[idx_];                             \
        }                                                                    \
    }

#define MFMA16(accv, bq, t)                                                  \
    __builtin_amdgcn_s_setprio(1);                                           \
    _Pragma("unroll")                                                        \
    for (int mr_ = 0; mr_ < 4; ++mr_) {                                      \
        _Pragma("unroll")                                                    \
        for (int nc_ = 0; nc_ < 4; ++nc_)                                    \
            accv[mr_][nc_] = __builtin_amdgcn_mfma_f32_16x16x32_bf16(        \
                areg[(t) & 1][mr_], bq[nc_], accv[mr_][nc_], 0, 0, 0);       \
    }                                                                        \
    __builtin_amdgcn_s_setprio(0);

// conv1 epilogue for one image: BN+ReLU -> LDS transpose -> yT store
#define EPI1(accv, nimg)                                                     \
    {                                                                        \
        ushort* T = B;                                                       \
        _Pragma("unroll")                                                    \
        for (int mr = 0; mr < 4; ++mr) {                                     \
            _Pragma("unroll")                                                \
            for (int nc = 0; nc < 4; ++nc) {                                 \
                int co0 = wv * 64 + mr * 16 + lg * 4;                        \
                float v0 = fmaxf(accv[mr][nc][0]*bnp[co0+0]+bnp[C_CH+co0+0],0.f);\
                float v1 = fmaxf(accv[mr][nc][1]*bnp[co0+1]+bnp[C_CH+co0+1],0.f);\
                float v2 = fmaxf(accv[mr][nc][2]*bnp[co0+2]+bnp[C_CH+co0+2],0.f);\
                float v3 = fmaxf(accv[mr][nc][3]*bnp[co0+3]+bnp[C_CH+co0+3],0.f);\
                uint2 pk;                                                    \
                pk.x = (uint)f2bf(v0) | ((uint)f2bf(v1) << 16);              \
                pk.y = (uint)f2bf(v2) | ((uint)f2bf(v3) << 16);              \
                *(uint2*)&T[(nc * 16 + lr) * 264 + co0] = pk;                \
            }                                                                \
        }                                                                    \
        __syncthreads();                                                     \
        ushort* yT = (ushort*)dst;                                           \
        _Pragma("unroll")                                                    \
        for (int it = 0; it < 8; ++it) {                                     \
            int slot = it * 256 + tid;                                       \
            int row = slot >> 5, g = slot & 31;                              \
            uint4v v = *(const uint4v*)&T[row * 264 + g * 8];                \
            *(uint4v*)(yT + ((size_t)(nimg) * HW_IMG + p0 + row) * C_CH + g * 8) = v;\
        }                                                                    \
        __syncthreads();                                                     \
    }

// conv2 epilogue for one image: BN + identity + ReLU, fp32 [n][co][p]
#define EPI2(accv, nimg)                                                     \
    {                                                                        \
        const size_t nbase = (size_t)(nimg) * CHW;                           \
        float* out = (float*)dst;                                            \
        _Pragma("unroll")                                                    \
        for (int mr = 0; mr < 4; ++mr) {                                     \
            _Pragma("unroll")                                                \
            for (int nc = 0; nc < 4; ++nc) {                                 \
                int pc = p0 + nc * 16 + lr;                                  \
                _Pragma("unroll")                                            \
                for (int i = 0; i < 4; ++i) {                                \
                    int co = wv * 64 + mr * 16 + lg * 4 + i;                 \
                    size_t o = nbase + (size_t)co * HW_IMG + pc;             \
                    float val = accv[mr][nc][i]*bnp[co] + bnp[C_CH+co] + ident[o];\
                    out[o] = fmaxf(val, 0.f);                                \
                }                                                            \
            }                                                                \
        }                                                                    \
    }

template<bool SECOND>
__global__ __launch_bounds__(256, 2) void conv_kernel(
    const ushort* __restrict__ srcT,    // [n][p][ci] bf16
    const ushort* __restrict__ wf,      // frag-packed weights
    const float* __restrict__ bnp,      // inv | add
    const float* __restrict__ ident,    // x fp32 (conv2)
    const ushort* __restrict__ zb,
    void* __restrict__ dst)
{
    // 2 windows x dbuf (61440B) + zero row; conv1 epilogue reuses base as T
    __shared__ ushort B[30760];

    const int tid = threadIdx.x;
    const int wv = tid >> 6, l = tid & 63;
    const int lr = l & 15, lg = l >> 4;

    int bid = blockIdx.x;
    int swz = (bid & 7) * 98 + (bid >> 3);    // XCD-chunked, bijective (784=8*98)
    const int npair = swz / 49, pt = swz % 49;
    const int n0 = npair * 2, n1 = n0 + 1;
    const int p0 = pt * 64;

    // W-border validity per nc (lane's output p = p0 + nc*16 + lr)
    bool wLa[4], wRa[4];
    int vbe[4];
#pragma unroll
    for (int nc = 0; nc < 4; ++nc) {
        int p = p0 + nc * 16 + lr;
        int w = p % 56;
        wLa[nc] = (w > 0);
        wRa[nc] = (w < 55);
        vbe[nc] = (64 + nc * 16 + lr) * RSTR + lg * 8;
    }
    const int zidx = ZROW + lg * 8;

    // staging: 960 slots of 16B per window-chunk; dest linear
    auto stage = [&](int nimg, int imgbase, int cix, int bufE) {
#pragma unroll
        for (int rd = 0; rd < 4; ++rd) {
            if (rd < 3 || tid < 192) {
                int slot = rd * 256 + tid;
                int row = slot / 5, g = slot - row * 5;
                int gp = p0 - 64 + row;
                bool val = (g < 4) && (gp >= 0) && (gp < HW_IMG);
                const ushort* src = val
                    ? (srcT + ((size_t)nimg * HW_IMG + gp) * C_CH + g * 8)
                    : (zb + g * 8);
                __builtin_amdgcn_global_load_lds(
                    (const __attribute__((address_space(1))) void*)(src + cix * 32),
                    (__attribute__((address_space(3))) void*)&B[imgbase + bufE + slot * 8],
                    16, 0, 0);
            }
        }
    };

    f32x4 acc0[4][4], acc1[4][4];
#pragma unroll
    for (int mr = 0; mr < 4; ++mr)
#pragma unroll
        for (int nc = 0; nc < 4; ++nc) {
            f32x4 z = {0.f, 0.f, 0.f, 0.f};
            acc0[mr][nc] = z;
            acc1[mr][nc] = z;
        }

    bf16x8 areg[2][4];
    const ushort* pWb = wf + wv * 2048 + l * 8;   // + (c*9+r)*8192 + mr*512

    auto loadA = [&](int t, bf16x8* a) {          // t compile-time
#pragma unroll
        for (int mr = 0; mr < 4; ++mr)
            a[mr] = *(const bf16x8*)(pWb + t * 8192 + mr * 512);
    };

    // prologue
    stage(n0, 0, 0, 0);
    stage(n1, IMG1B, 0, 0);
    if (tid < 40) B[ZROW + tid] = 0;
    loadA(0, areg[0]);
    __syncthreads();

#pragma unroll
    for (int c = 0; c < NCH; ++c) {
        const int b0 = (c & 1) ? BUFE : 0;
        bf16x8 bq0[4], bq1[4];
#pragma unroll
        for (int s = 0; s < 9; ++s) {
            const int t = c * 9 + s;
            if (t + 1 < NSTEP) loadA(t + 1, areg[(t + 1) & 1]);
            if (s == 3 && c + 1 < NCH) stage(n0, 0, c + 1, b0 ^ BUFE);
            if (s == 4 && c + 1 < NCH) stage(n1, IMG1B, c + 1, b0 ^ BUFE);
            READB(bq0, b0, s);
            MFMA16(acc0, bq0, t);
            READB(bq1, IMG1B + b0, s);
            MFMA16(acc1, bq1, t);
        }
        __syncthreads();
    }

    if constexpr (!SECOND) {
        EPI1(acc0, n0);
        EPI1(acc1, n1);
    } else {
        EPI2(acc0, n0);
        EPI2(acc1, n1);
    }
}

extern "C" void kernel_launch(void* const* d_in, const int* in_sizes, int n_in,
                              void* d_out, int out_size, void* d_ws, size_t ws_size,
                              hipStream_t stream) {
    const float* x  = (const float*)d_in[0];
    const float* w1 = (const float*)d_in[1];
    const float* g1 = (const float*)d_in[2];
    const float* b1 = (const float*)d_in[3];
    const float* m1 = (const float*)d_in[4];
    const float* v1 = (const float*)d_in[5];
    const float* w2 = (const float*)d_in[6];
    const float* g2 = (const float*)d_in[7];
    const float* b2 = (const float*)d_in[8];
    const float* m2 = (const float*)d_in[9];
    const float* v2 = (const float*)d_in[10];

    ushort* wf1 = (ushort*)d_ws;
    ushort* wf2 = wf1 + WELEM;
    float*  bn  = (float*)(wf2 + WELEM);
    ushort* zb  = (ushort*)(bn + 4 * C_CH);
    ushort* yT  = zb + 512;
    ushort* xT  = (ushort*)d_out;   // scratch in d_out; conv2 overwrites fully

    prep_kernel<<<dim3(4608), dim3(256), 0, stream>>>(
        w1, w2, g1, b1, m1, v1, g2, b2, m2, v2, wf1, wf2, bn, zb);

    xpose_kernel<<<dim3(6272), dim3(256), 0, stream>>>(x, xT);

    conv_kernel<false><<<dim3(784), dim3(256), 0, stream>>>(
        xT, wf1, bn, x, zb, (void*)yT);

    conv_kernel<true><<<dim3(784), dim3(256), 0, stream>>>(
        yT, wf2, bn + 512, x, zb, d_out);
}

// Round 15
// 251.900 us; speedup vs baseline: 1.8981x; 1.8981x over previous
//
#include <hip/hip_runtime.h>
#include <hip/hip_bf16.h>

// BasicBlock via chunked shift-GEMM bf16 MFMA. R14 = R6's full pipeline at
// R9's register cap: depth-2 A-prefetch (areg[3]) + 1-tap B prefetch
// (bqA/bqB named arrays) + address-select zero-row masking, all under
// __launch_bounds__(256,2) (cap 256; R6 spilled only because (256,3)'s
// ~168 cap couldn't hold ~190 unified regs; R9 proved 176 fits w/o spill
// at the same 2 waves/SIMD). Estimated ~194 unified -> 2 w/SIMD, 60-reg
// margin. Structure: 256co x 64p block, ci in 8 chunks of 32; 192-row
// window staged via global_load_lds at s==3; 9 tap-steps/chunk; setprio
// on MFMA clusters; XCD-chunked swizzle.

typedef __attribute__((ext_vector_type(8))) short bf16x8;
typedef __attribute__((ext_vector_type(4))) float f32x4;
typedef __attribute__((ext_vector_type(4))) unsigned int uint4v;

#define C_CH   256
#define HW_IMG 3136
#define CHW    802816     // 256*3136
#define WELEM  589824     // 256*2304
#define RSTR   40         // LDS row stride in ushorts (32 data + 8 pad) = 80B
#define BUFE   7680       // 192*40 ushorts per buffer (15360B)
#define NCH    8          // ci chunks of 32
#define NSTEP  72         // 8 chunks * 9 taps
#define ZROW   15360      // zero row (40 ushorts) after both buffers

__device__ __forceinline__ ushort f2bf(float f){
    union{__hip_bfloat16 h; ushort u;} c; c.h = __float2bfloat16(f); return c.u;
}

__global__ __launch_bounds__(256) void prep_kernel(
    const float* __restrict__ w1, const float* __restrict__ w2,
    const float* __restrict__ g1, const float* __restrict__ b1,
    const float* __restrict__ m1, const float* __restrict__ v1,
    const float* __restrict__ g2, const float* __restrict__ b2,
    const float* __restrict__ m2, const float* __restrict__ v2,
    ushort* __restrict__ wf1, ushort* __restrict__ wf2,
    float* __restrict__ bn, ushort* __restrict__ zb)
{
    int gid = blockIdx.x * 256 + threadIdx.x;
    // frag-packed: d = (((c*9+r)*16 + ct)*64 + l)*8 + j
    // co = ct*16 + (l&15), ci = c*32 + (l>>4)*8 + j, tap r
    if (gid < WELEM) {
        int j = gid & 7, l = (gid >> 3) & 63, ct = (gid >> 9) & 15, rr = gid >> 13;
        int c = rr / 9, r = rr - c * 9;
        int co = ct * 16 + (l & 15);
        int ci = c * 32 + (l >> 4) * 8 + j;
        wf1[gid] = f2bf(w1[(co * C_CH + ci) * 9 + r]);
    }
    int g2i = gid - WELEM;
    if (g2i >= 0 && g2i < WELEM) {
        int j = g2i & 7, l = (g2i >> 3) & 63, ct = (g2i >> 9) & 15, rr = g2i >> 13;
        int c = rr / 9, r = rr - c * 9;
        int co = ct * 16 + (l & 15);
        int ci = c * 32 + (l >> 4) * 8 + j;
        wf2[g2i] = f2bf(w2[(co * C_CH + ci) * 9 + r]);
    }
    if (gid < C_CH) {
        float i1 = g1[gid] * rsqrtf(v1[gid] + 1e-5f);
        bn[gid]            = i1;
        bn[C_CH + gid]     = b1[gid] - m1[gid] * i1;
        float i2 = g2[gid] * rsqrtf(v2[gid] + 1e-5f);
        bn[2*C_CH + gid]   = i2;
        bn[3*C_CH + gid]   = b2[gid] - m2[gid] * i2;
    }
    if (gid < 512) zb[gid] = 0;
}

// x [n][ci][p] f32 -> xT [n][p][ci] bf16
__global__ __launch_bounds__(256) void xpose_kernel(
    const float* __restrict__ x, ushort* __restrict__ xT)
{
    __shared__ ushort T[64 * 72];
    int tid = threadIdx.x;
    int b = blockIdx.x;                  // 32*49*4
    int n = b / 196, rem = b % 196;
    int pb = rem >> 2, cb = rem & 3;
    int lane = tid & 63, cr = tid >> 6;
    const float* xp = x + ((size_t)(n * C_CH + cb * 64)) * HW_IMG + pb * 64 + lane;
#pragma unroll
    for (int j = 0; j < 16; ++j) {
        int cil = cr * 16 + j;
        T[lane * 72 + cil] = f2bf(xp[(size_t)cil * HW_IMG]);
    }
    __syncthreads();
#pragma unroll
    for (int it = 0; it < 2; ++it) {
        int slot = it * 256 + tid;       // 512 slots = 64 rows x 8 granules
        int p = slot >> 3, g = slot & 7;
        uint4v v = *(const uint4v*)&T[p * 72 + g * 8];
        *(uint4v*)(xT + ((size_t)n * HW_IMG + pb * 64 + p) * C_CH + cb * 64 + g * 8) = v;
    }
}

// read tap s's 4 B-frags into NAMED array `dst` (address-select zero row)
#define READB(dst, bufE, s)                                                  \
    {                                                                        \
        const int dw_ = (s) % 3 - 1;                                         \
        const int off_ = ((s) / 3 - 1) * 56 * RSTR + dw_ * RSTR + (bufE);    \
        _Pragma("unroll")                                                    \
        for (int nc_ = 0; nc_ < 4; ++nc_) {                                  \
            bool ok_ = (dw_ == -1) ? wLa[nc_]                                \
                                   : ((dw_ == 1) ? wRa[nc_] : true);         \
            int idx_ = ok_ ? (vbe[nc_] + off_) : zidx;                       \
            dst[nc_] = *(const bf16x8*)&B[idx_];                             \
        }                                                                    \
    }

#define MFMA16(bq, t)                                                        \
    __builtin_amdgcn_s_setprio(1);                                           \
    _Pragma("unroll")                                                        \
    for (int mr_ = 0; mr_ < 4; ++mr_) {                                      \
        _Pragma("unroll")                                                    \
        for (int nc_ = 0; nc_ < 4; ++nc_)                                    \
            acc[mr_][nc_] = __builtin_amdgcn_mfma_f32_16x16x32_bf16(         \
                areg[(t) % 3][mr_], bq[nc_], acc[mr_][nc_], 0, 0, 0);        \
    }                                                                        \
    __builtin_amdgcn_s_setprio(0);

template<bool SECOND>
__global__ __launch_bounds__(256, 2) void conv_kernel(
    const ushort* __restrict__ srcT,    // [n][p][ci] bf16
    const ushort* __restrict__ wf,      // frag-packed weights
    const float* __restrict__ bnp,      // inv | add
    const float* __restrict__ ident,    // x fp32 (conv2)
    const ushort* __restrict__ zb,
    void* __restrict__ dst)
{
    // dbuf 2*15360B + zero row; conv1 epilogue reuses as 64x264 transpose
    __shared__ ushort B[16896];

    const int tid = threadIdx.x;
    const int wv = tid >> 6, l = tid & 63;
    const int lr = l & 15, lg = l >> 4;

    int bid = blockIdx.x;
    int swz = (bid & 7) * 196 + (bid >> 3);   // XCD-chunked, bijective (1568=8*196)
    const int n = swz / 49, pt = swz % 49;
    const int p0 = pt * 64;

    // W-border validity per nc (lane's output p = p0 + nc*16 + lr)
    bool wLa[4], wRa[4];
    int vbe[4];
#pragma unroll
    for (int nc = 0; nc < 4; ++nc) {
        int p = p0 + nc * 16 + lr;
        int w = p % 56;
        wLa[nc] = (w > 0);
        wRa[nc] = (w < 55);
        vbe[nc] = (64 + nc * 16 + lr) * RSTR + lg * 8;   // B-frag LDS base (ushort)
    }
    const int zidx = ZROW + lg * 8;      // zero-row read address

    // staging: 960 slots of 16B per chunk; dest linear (row*80B+g*16B = slot*16B)
    const ushort* sA[4];
#pragma unroll
    for (int rd = 0; rd < 4; ++rd) {
        int slot = rd * 256 + tid;
        int row = slot / 5, g = slot - row * 5;
        int gp = p0 - 64 + row;
        bool val = (g < 4) && (gp >= 0) && (gp < HW_IMG) && (slot < 960);
        sA[rd] = val ? (srcT + ((size_t)n * HW_IMG + gp) * C_CH + g * 8)
                     : (zb + g * 8);
    }

    auto stage = [&](int cix, int bufE) {
#pragma unroll
        for (int rd = 0; rd < 4; ++rd) {
            if (rd < 3 || tid < 192) {
                __builtin_amdgcn_global_load_lds(
                    (const __attribute__((address_space(1))) void*)(sA[rd] + cix * 32),
                    (__attribute__((address_space(3))) void*)&B[bufE + (rd * 256 + tid) * 8],
                    16, 0, 0);
            }
        }
    };

    f32x4 acc[4][4];
#pragma unroll
    for (int mr = 0; mr < 4; ++mr)
#pragma unroll
        for (int nc = 0; nc < 4; ++nc) {
            f32x4 z = {0.f, 0.f, 0.f, 0.f};
            acc[mr][nc] = z;
        }

    bf16x8 areg[3][4];
    const ushort* pWb = wf + wv * 2048 + l * 8;   // + (c*9+r)*8192 + mr*512

    auto loadA = [&](int t, bf16x8* a) {          // t compile-time
#pragma unroll
        for (int mr = 0; mr < 4; ++mr)
            a[mr] = *(const bf16x8*)(pWb + t * 8192 + mr * 512);
    };

    // prologue
    stage(0, 0);
    if (tid < 40) B[ZROW + tid] = 0;
    loadA(0, areg[0]);
    loadA(1, areg[1]);
    __syncthreads();

#pragma unroll
    for (int c = 0; c < NCH; ++c) {
        const int bufE = (c & 1) ? BUFE : 0;
        bf16x8 bqA[4], bqB[4];
        READB(bqA, bufE, 0);
#pragma unroll
        for (int s = 0; s < 9; ++s) {
            const int t = c * 9 + s;
            if (t + 2 < NSTEP) loadA(t + 2, areg[(t + 2) % 3]);
            if (s == 3 && c + 1 < NCH) stage(c + 1, bufE ^ BUFE);
            if ((s & 1) == 0) {
                if (s + 1 < 9) READB(bqB, bufE, s + 1);
                MFMA16(bqA, t);
            } else {
                READB(bqA, bufE, s + 1);   // s+1 <= 8
                MFMA16(bqB, t);
            }
        }
        __syncthreads();
    }

    if constexpr (!SECOND) {
        // epilogue: BN+ReLU, LDS-transpose to yT [n][p][co] bf16
        ushort* T = B;                  // [64 p][264] (256 co + 8 pad)
#pragma unroll
        for (int mr = 0; mr < 4; ++mr) {
#pragma unroll
            for (int nc = 0; nc < 4; ++nc) {
                int co0 = wv * 64 + mr * 16 + lg * 4;
                float v0 = fmaxf(acc[mr][nc][0] * bnp[co0+0] + bnp[C_CH+co0+0], 0.f);
                float v1 = fmaxf(acc[mr][nc][1] * bnp[co0+1] + bnp[C_CH+co0+1], 0.f);
                float v2 = fmaxf(acc[mr][nc][2] * bnp[co0+2] + bnp[C_CH+co0+2], 0.f);
                float v3 = fmaxf(acc[mr][nc][3] * bnp[co0+3] + bnp[C_CH+co0+3], 0.f);
                uint2 pk;
                pk.x = (uint)f2bf(v0) | ((uint)f2bf(v1) << 16);
                pk.y = (uint)f2bf(v2) | ((uint)f2bf(v3) << 16);
                *(uint2*)&T[(nc * 16 + lr) * 264 + co0] = pk;
            }
        }
        __syncthreads();
        ushort* yT = (ushort*)dst;
#pragma unroll
        for (int it = 0; it < 8; ++it) {
            int slot = it * 256 + tid;  // 2048 slots = 64 rows x 32 granules
            int row = slot >> 5, g = slot & 31;
            uint4v v = *(const uint4v*)&T[row * 264 + g * 8];
            *(uint4v*)(yT + ((size_t)n * HW_IMG + p0 + row) * C_CH + g * 8) = v;
        }
    } else {
        // epilogue: BN + identity + ReLU, fp32 out [n][co][p]
        const size_t nbase = (size_t)n * CHW;
        float* out = (float*)dst;
#pragma unroll
        for (int mr = 0; mr < 4; ++mr) {
#pragma unroll
            for (int nc = 0; nc < 4; ++nc) {
                int pc = p0 + nc * 16 + lr;
#pragma unroll
                for (int i = 0; i < 4; ++i) {
                    int co = wv * 64 + mr * 16 + lg * 4 + i;
                    size_t o = nbase + (size_t)co * HW_IMG + pc;
                    float val = acc[mr][nc][i] * bnp[co] + bnp[C_CH + co] + ident[o];
                    out[o] = fmaxf(val, 0.f);
                }
            }
        }
    }
}

extern "C" void kernel_launch(void* const* d_in, const int* in_sizes, int n_in,
                              void* d_out, int out_size, void* d_ws, size_t ws_size,
                              hipStream_t stream) {
    const float* x  = (const float*)d_in[0];
    const float* w1 = (const float*)d_in[1];
    const float* g1 = (const float*)d_in[2];
    const float* b1 = (const float*)d_in[3];
    const float* m1 = (const float*)d_in[4];
    const float* v1 = (const float*)d_in[5];
    const float* w2 = (const float*)d_in[6];
    const float* g2 = (const float*)d_in[7];
    const float* b2 = (const float*)d_in[8];
    const float* m2 = (const float*)d_in[9];
    const float* v2 = (const float*)d_in[10];

    ushort* wf1 = (ushort*)d_ws;
    ushort* wf2 = wf1 + WELEM;
    float*  bn  = (float*)(wf2 + WELEM);
    ushort* zb  = (ushort*)(bn + 4 * C_CH);
    ushort* yT  = zb + 512;
    ushort* xT  = (ushort*)d_out;   // scratch in d_out; conv2 overwrites fully

    prep_kernel<<<dim3(4608), dim3(256), 0, stream>>>(
        w1, w2, g1, b1, m1, v1, g2, b2, m2, v2, wf1, wf2, bn, zb);

    xpose_kernel<<<dim3(6272), dim3(256), 0, stream>>>(x, xT);

    conv_kernel<false><<<dim3(1568), dim3(256), 0, stream>>>(
        xT, wf1, bn, x, zb, (void*)yT);

    conv_kernel<true><<<dim3(1568), dim3(256), 0, stream>>>(
        yT, wf2, bn + 512, x, zb, d_out);
}